// Round 8
// baseline (274.528 us; speedup 1.0000x reference)
//
#include <hip/hip_runtime.h>

// FP8DynamicLinear: x[8192,2048] fp32 -> dynamic per-tensor fp8 quant,
// qweight[2048,2048] (fp8-representable fp32), out = (qx*xs) @ (qw*ws)^T + bias.
static constexpr int M_ = 8192;
static constexpr int K_ = 2048;
static constexpr int N_ = 2048;

#define FP8MAX 448.0f

using f32x4 = __attribute__((ext_vector_type(4))) float;
typedef unsigned int u32;
typedef unsigned char u8;

__device__ __forceinline__ void gload_lds16(const void* g, void* lds) {
  __builtin_amdgcn_global_load_lds((const __attribute__((address_space(1))) void*)g,
                                   (__attribute__((address_space(3))) void*)lds,
                                   16 /*bytes*/, 0 /*offset*/, 0 /*aux*/);
}

// ---------------- pass 1: amax(|x|) ----------------
__global__ void amax_abs_kernel(const float* __restrict__ x, u32* __restrict__ amax_bits, int n4) {
  const float4* x4 = (const float4*)x;
  float m = 0.f;
  int idx = blockIdx.x * blockDim.x + threadIdx.x;
  int stride = gridDim.x * blockDim.x;
  for (int i = idx; i < n4; i += stride) {
    float4 v = x4[i];
    m = fmaxf(m, fmaxf(fmaxf(fabsf(v.x), fabsf(v.y)), fmaxf(fabsf(v.z), fabsf(v.w))));
  }
  #pragma unroll
  for (int off = 32; off > 0; off >>= 1) m = fmaxf(m, __shfl_xor(m, off, 64));
  if ((threadIdx.x & 63) == 0) atomicMax(amax_bits, __float_as_uint(m));  // m>=0: uint order == float order
}

// ---------------- pass 2: quantize x -> fp8 e4m3 (RNE, matches clip+cast) ----------------
// Unit-stride: one float4 per thread per iter (16B/lane loads, 4B/lane stores).
__global__ void quant_x_kernel(const float* __restrict__ x, const u32* __restrict__ amax_bits,
                               u32* __restrict__ qx, int n4) {
  float amax = __uint_as_float(*amax_bits);
  float scale = FP8MAX / fmaxf(amax, 1e-12f);
  const f32x4* x4 = (const f32x4*)x;
  int idx = blockIdx.x * blockDim.x + threadIdx.x;
  int stride = gridDim.x * blockDim.x;
  for (int i = idx; i < n4; i += stride) {
    f32x4 v = x4[i];
    #pragma unroll
    for (int e = 0; e < 4; ++e) v[e] = fminf(fmaxf(v[e] * scale, -FP8MAX), FP8MAX);
    int p = __builtin_amdgcn_cvt_pk_fp8_f32(v[0], v[1], 0, false);
    p = __builtin_amdgcn_cvt_pk_fp8_f32(v[2], v[3], p, true);
    qx[i] = (u32)p;
  }
}

// ---------------- pass 3: cast qweight (already fp8-representable) -> fp8 bytes ----------------
__global__ void quant_w_kernel(const float* __restrict__ wsrc, u32* __restrict__ qw, int n4) {
  const f32x4* w4 = (const f32x4*)wsrc;
  int idx = blockIdx.x * blockDim.x + threadIdx.x;
  int stride = gridDim.x * blockDim.x;
  for (int i = idx; i < n4; i += stride) {
    f32x4 v = w4[i];
    int p = __builtin_amdgcn_cvt_pk_fp8_f32(v[0], v[1], 0, false);
    p = __builtin_amdgcn_cvt_pk_fp8_f32(v[2], v[3], p, true);
    qw[i] = (u32)p;
  }
}

// ---------------- pass 4: fp8 GEMM, C = (qx qw^T) * (xs*ws) + bias ----------------
// 128x128 tile, BK=64 bytes, 4 waves (2x2), 16x16x32 fp8 MFMA.
// Minimum 2-phase pipeline (catalog T3-min, m248v2): double-buffered LDS;
// STAGE(t+1) issued BEFORE compute(t); raw s_barrier + explicit vmcnt(0) once per tile.
// LDS swizzle: chunk ^= (row>>2)&3 via pre-swizzled GLOBAL source (rule 21).
//   Read pattern: half-wave 2-deep (free, m136), full-wave 4-deep (= b64 floor).
__global__ __launch_bounds__(256, 2) void gemm_fp8_kernel(
    const u8* __restrict__ qx, const u8* __restrict__ qw,
    const u32* __restrict__ amax_bits, const float* __restrict__ wscale_p,
    const float* __restrict__ bias, float* __restrict__ out)
{
  constexpr int BM = 128, BN = 128, BK = 64;
  constexpr int NT = K_ / BK;  // 32
  __shared__ u8 As[2][BM * BK];
  __shared__ u8 Bs[2][BN * BK];

  const int tid  = threadIdx.x;
  const int wave = tid >> 6;
  const int lane = tid & 63;
  const int bm = blockIdx.y * BM;
  const int bn = blockIdx.x * BN;

  // ---- staging addressing: thread tid stages 16B chunk `tid` (call 0) and `tid+256` (call 1)
  const int sr = tid >> 2;                      // LDS row 0..63 (call 0), +64 for call 1
  const int sc = tid & 3;                       // 16B chunk-in-row
  const int swzc = (sc ^ ((sr >> 2) & 3)) << 4; // pre-swizzled global byte offset in row
  const u8* gA0 = qx + (size_t)(bm + sr) * K_ + swzc;
  const u8* gA1 = gA0 + (size_t)64 * K_;
  const u8* gB0 = qw + (size_t)(bn + sr) * K_ + swzc;
  const u8* gB1 = gB0 + (size_t)64 * K_;
  const int ldsOff0 = wave * 1024;              // wave-uniform LDS bases
  const int ldsOff1 = 4096 + wave * 1024;

  // ---- fragment addressing
  const int wr = wave >> 1, wc = wave & 1;
  const int fr = lane & 15;                     // row within 16x16 tile
  const int q  = lane >> 4;                     // k-group
  const int swz = ((fr >> 2) & 3) << 4;         // read-side un-swizzle ((row>>2)&3 == (fr>>2)&3)
  int rowA[4], rowB[4];
  #pragma unroll
  for (int m = 0; m < 4; ++m) rowA[m] = (wr * 64 + m * 16 + fr) * BK;
  #pragma unroll
  for (int n = 0; n < 4; ++n) rowB[n] = (wc * 64 + n * 16 + fr) * BK;

  f32x4 acc[4][4];
  #pragma unroll
  for (int m = 0; m < 4; ++m)
    #pragma unroll
    for (int n = 0; n < 4; ++n)
      acc[m][n] = f32x4{0.f, 0.f, 0.f, 0.f};

  auto STAGE = [&](int buf) {
    gload_lds16(gA0, &As[buf][ldsOff0]);
    gload_lds16(gA1, &As[buf][ldsOff1]);
    gload_lds16(gB0, &Bs[buf][ldsOff0]);
    gload_lds16(gB1, &Bs[buf][ldsOff1]);
    gA0 += BK; gA1 += BK; gB0 += BK; gB1 += BK;
  };

  auto COMPUTE = [&](int buf) {
    #pragma unroll
    for (int ks = 0; ks < 2; ++ks) {
      const int kb = (ks * 32 + q * 8) ^ swz;
      long a[4], b[4];
      #pragma unroll
      for (int m = 0; m < 4; ++m) a[m] = *(const long*)(&As[buf][0] + rowA[m] + kb);
      #pragma unroll
      for (int n = 0; n < 4; ++n) b[n] = *(const long*)(&Bs[buf][0] + rowB[n] + kb);
      #pragma unroll
      for (int m = 0; m < 4; ++m)
        #pragma unroll
        for (int n = 0; n < 4; ++n)
          acc[m][n] = __builtin_amdgcn_mfma_f32_16x16x32_fp8_fp8(a[m], b[n], acc[m][n], 0, 0, 0);
    }
  };

  // prologue: stage tile 0, wait, barrier
  STAGE(0);
  asm volatile("s_waitcnt vmcnt(0)" ::: "memory");
  __builtin_amdgcn_s_barrier();

  int cur = 0;
  for (int kt = 0; kt < NT - 1; ++kt) {
    STAGE(cur ^ 1);                  // issue next-tile loads (stay in flight over MFMA)
    COMPUTE(cur);                    // ds_read + MFMA on current tile
    asm volatile("s_waitcnt vmcnt(0)" ::: "memory");  // prefetch landed
    __builtin_amdgcn_s_barrier();    // all waves done reading buf[cur] too
    cur ^= 1;
  }
  COMPUTE(cur);                      // last tile, no prefetch

  // ---- epilogue: scale + bias, C/D layout: col=lane&15, row=(lane>>4)*4+reg
  float amax = __uint_as_float(*amax_bits);
  float scale = FP8MAX / fmaxf(amax, 1e-12f);
  float xs = 1.0f / scale;
  float cs = xs * wscale_p[0];
  const int orow = bm + wr * 64;
  const int ocol = bn + wc * 64;
  #pragma unroll
  for (int m = 0; m < 4; ++m) {
    #pragma unroll
    for (int n = 0; n < 4; ++n) {
      const int col = ocol + n * 16 + fr;
      const float bv = bias[col];
      #pragma unroll
      for (int i = 0; i < 4; ++i) {
        const int row = orow + m * 16 + q * 4 + i;
        out[(size_t)row * N_ + col] = acc[m][n][i] * cs + bv;
      }
    }
  }
}

extern "C" void kernel_launch(void* const* d_in, const int* in_sizes, int n_in,
                              void* d_out, int out_size, void* d_ws, size_t ws_size,
                              hipStream_t stream) {
  const float* x       = (const float*)d_in[0];
  const float* qweight = (const float*)d_in[1];
  const float* wscale  = (const float*)d_in[2];
  const float* bias    = (const float*)d_in[3];
  float* out = (float*)d_out;

  u32* amax_bits = (u32*)d_ws;
  u8* qx = (u8*)d_ws + 256;
  u8* qw = qx + (size_t)M_ * K_;

  hipMemsetAsync(d_ws, 0, 256, stream);  // amax slot must start at 0 (ws is poisoned 0xAA)
  amax_abs_kernel<<<2048, 256, 0, stream>>>(x, amax_bits, M_ * K_ / 4);
  quant_x_kernel<<<2048, 256, 0, stream>>>(x, amax_bits, (u32*)qx, M_ * K_ / 4);
  quant_w_kernel<<<2048, 256, 0, stream>>>(qweight, (u32*)qw, N_ * K_ / 4);
  dim3 grid(N_ / 128, M_ / 128);
  gemm_fp8_kernel<<<grid, 256, 0, stream>>>(qx, qw, amax_bits, wscale, bias, out);
}

// Round 9
// 190.964 us; speedup vs baseline: 1.4376x; 1.4376x over previous
//
#include <hip/hip_runtime.h>

// FP8DynamicLinear: x[8192,2048] fp32 -> dynamic per-tensor fp8 quant,
// qweight[2048,2048] (fp8-representable fp32), out = (qx*xs) @ (qw*ws)^T + bias.
static constexpr int M_ = 8192;
static constexpr int K_ = 2048;
static constexpr int N_ = 2048;
static constexpr int AMAX_BLOCKS = 2048;

#define FP8MAX 448.0f

using f32x4 = __attribute__((ext_vector_type(4))) float;
typedef unsigned int u32;
typedef unsigned char u8;

__device__ __forceinline__ void gload_lds16(const void* g, void* lds) {
  __builtin_amdgcn_global_load_lds((const __attribute__((address_space(1))) void*)g,
                                   (__attribute__((address_space(3))) void*)lds,
                                   16 /*bytes*/, 0 /*offset*/, 0 /*aux*/);
}

// ---------------- pass 1a: per-block partial amax(|x|) — NO global atomics ----------------
__global__ void amax_partial_kernel(const float* __restrict__ x, float* __restrict__ partial, int n4) {
  __shared__ float smax[4];
  const float4* x4 = (const float4*)x;
  float m = 0.f;
  int idx = blockIdx.x * blockDim.x + threadIdx.x;
  int stride = gridDim.x * blockDim.x;
  for (int i = idx; i < n4; i += stride) {
    float4 v = x4[i];
    m = fmaxf(m, fmaxf(fmaxf(fabsf(v.x), fabsf(v.y)), fmaxf(fabsf(v.z), fabsf(v.w))));
  }
  #pragma unroll
  for (int off = 32; off > 0; off >>= 1) m = fmaxf(m, __shfl_xor(m, off, 64));
  const int wave = threadIdx.x >> 6;
  if ((threadIdx.x & 63) == 0) smax[wave] = m;
  __syncthreads();
  if (threadIdx.x == 0)
    partial[blockIdx.x] = fmaxf(fmaxf(smax[0], smax[1]), fmaxf(smax[2], smax[3]));
}

// ---------------- pass 1b: reduce 2048 partials -> amax bits (1 block) ----------------
__global__ void amax_final_kernel(const float* __restrict__ partial, u32* __restrict__ amax_bits, int n) {
  __shared__ float smax[4];
  float m = 0.f;
  for (int i = threadIdx.x; i < n; i += blockDim.x) m = fmaxf(m, partial[i]);
  #pragma unroll
  for (int off = 32; off > 0; off >>= 1) m = fmaxf(m, __shfl_xor(m, off, 64));
  const int wave = threadIdx.x >> 6;
  if ((threadIdx.x & 63) == 0) smax[wave] = m;
  __syncthreads();
  if (threadIdx.x == 0) {
    float a = fmaxf(fmaxf(smax[0], smax[1]), fmaxf(smax[2], smax[3]));
    amax_bits[0] = __float_as_uint(a);
  }
}

// ---------------- pass 2: quantize x -> fp8 e4m3 (RNE, matches clip+cast) ----------------
// Unit-stride: one float4 per thread per iter (16B/lane loads, 4B/lane stores).
__global__ void quant_x_kernel(const float* __restrict__ x, const u32* __restrict__ amax_bits,
                               u32* __restrict__ qx, int n4) {
  float amax = __uint_as_float(*amax_bits);
  float scale = FP8MAX / fmaxf(amax, 1e-12f);
  const f32x4* x4 = (const f32x4*)x;
  int idx = blockIdx.x * blockDim.x + threadIdx.x;
  int stride = gridDim.x * blockDim.x;
  for (int i = idx; i < n4; i += stride) {
    f32x4 v = x4[i];
    #pragma unroll
    for (int e = 0; e < 4; ++e) v[e] = fminf(fmaxf(v[e] * scale, -FP8MAX), FP8MAX);
    int p = __builtin_amdgcn_cvt_pk_fp8_f32(v[0], v[1], 0, false);
    p = __builtin_amdgcn_cvt_pk_fp8_f32(v[2], v[3], p, true);
    qx[i] = (u32)p;
  }
}

// ---------------- pass 3: cast qweight (already fp8-representable) -> fp8 bytes ----------------
__global__ void quant_w_kernel(const float* __restrict__ wsrc, u32* __restrict__ qw, int n4) {
  const f32x4* w4 = (const f32x4*)wsrc;
  int idx = blockIdx.x * blockDim.x + threadIdx.x;
  int stride = gridDim.x * blockDim.x;
  for (int i = idx; i < n4; i += stride) {
    f32x4 v = w4[i];
    int p = __builtin_amdgcn_cvt_pk_fp8_f32(v[0], v[1], 0, false);
    p = __builtin_amdgcn_cvt_pk_fp8_f32(v[2], v[3], p, true);
    qw[i] = (u32)p;
  }
}

// ---------------- pass 4: fp8 GEMM, C = (qx qw^T) * (xs*ws) + bias ----------------
// 128x128 tile, BK=64 bytes, 4 waves (2x2), 16x16x32 fp8 MFMA.
// Minimum 2-phase pipeline (catalog T3-min, m248v2): double-buffered LDS;
// STAGE(t+1) issued BEFORE compute(t); raw s_barrier + explicit vmcnt(0) once per tile.
// LDS swizzle: chunk ^= (row>>2)&3 via pre-swizzled GLOBAL source (rule 21).
//   Read pattern: half-wave 2-deep (free, m136), full-wave 4-deep (= b64 floor).
__global__ __launch_bounds__(256, 2) void gemm_fp8_kernel(
    const u8* __restrict__ qx, const u8* __restrict__ qw,
    const u32* __restrict__ amax_bits, const float* __restrict__ wscale_p,
    const float* __restrict__ bias, float* __restrict__ out)
{
  constexpr int BM = 128, BN = 128, BK = 64;
  constexpr int NT = K_ / BK;  // 32
  __shared__ u8 As[2][BM * BK];
  __shared__ u8 Bs[2][BN * BK];

  const int tid  = threadIdx.x;
  const int wave = tid >> 6;
  const int lane = tid & 63;
  const int bm = blockIdx.y * BM;
  const int bn = blockIdx.x * BN;

  // ---- staging addressing: thread tid stages 16B chunk `tid` (call 0) and `tid+256` (call 1)
  const int sr = tid >> 2;                      // LDS row 0..63 (call 0), +64 for call 1
  const int sc = tid & 3;                       // 16B chunk-in-row
  const int swzc = (sc ^ ((sr >> 2) & 3)) << 4; // pre-swizzled global byte offset in row
  const u8* gA0 = qx + (size_t)(bm + sr) * K_ + swzc;
  const u8* gA1 = gA0 + (size_t)64 * K_;
  const u8* gB0 = qw + (size_t)(bn + sr) * K_ + swzc;
  const u8* gB1 = gB0 + (size_t)64 * K_;
  const int ldsOff0 = wave * 1024;              // wave-uniform LDS bases
  const int ldsOff1 = 4096 + wave * 1024;

  // ---- fragment addressing
  const int wr = wave >> 1, wc = wave & 1;
  const int fr = lane & 15;                     // row within 16x16 tile
  const int q  = lane >> 4;                     // k-group
  const int swz = ((fr >> 2) & 3) << 4;         // read-side un-swizzle ((row>>2)&3 == (fr>>2)&3)
  int rowA[4], rowB[4];
  #pragma unroll
  for (int m = 0; m < 4; ++m) rowA[m] = (wr * 64 + m * 16 + fr) * BK;
  #pragma unroll
  for (int n = 0; n < 4; ++n) rowB[n] = (wc * 64 + n * 16 + fr) * BK;

  f32x4 acc[4][4];
  #pragma unroll
  for (int m = 0; m < 4; ++m)
    #pragma unroll
    for (int n = 0; n < 4; ++n)
      acc[m][n] = f32x4{0.f, 0.f, 0.f, 0.f};

  auto STAGE = [&](int buf) {
    gload_lds16(gA0, &As[buf][ldsOff0]);
    gload_lds16(gA1, &As[buf][ldsOff1]);
    gload_lds16(gB0, &Bs[buf][ldsOff0]);
    gload_lds16(gB1, &Bs[buf][ldsOff1]);
    gA0 += BK; gA1 += BK; gB0 += BK; gB1 += BK;
  };

  auto COMPUTE = [&](int buf) {
    #pragma unroll
    for (int ks = 0; ks < 2; ++ks) {
      const int kb = (ks * 32 + q * 8) ^ swz;
      long a[4], b[4];
      #pragma unroll
      for (int m = 0; m < 4; ++m) a[m] = *(const long*)(&As[buf][0] + rowA[m] + kb);
      #pragma unroll
      for (int n = 0; n < 4; ++n) b[n] = *(const long*)(&Bs[buf][0] + rowB[n] + kb);
      #pragma unroll
      for (int m = 0; m < 4; ++m)
        #pragma unroll
        for (int n = 0; n < 4; ++n)
          acc[m][n] = __builtin_amdgcn_mfma_f32_16x16x32_fp8_fp8(a[m], b[n], acc[m][n], 0, 0, 0);
    }
  };

  // prologue: stage tile 0, wait, barrier
  STAGE(0);
  asm volatile("s_waitcnt vmcnt(0)" ::: "memory");
  __builtin_amdgcn_s_barrier();

  int cur = 0;
  for (int kt = 0; kt < NT - 1; ++kt) {
    STAGE(cur ^ 1);                  // issue next-tile loads (stay in flight over MFMA)
    COMPUTE(cur);                    // ds_read + MFMA on current tile
    asm volatile("s_waitcnt vmcnt(0)" ::: "memory");  // prefetch landed
    __builtin_amdgcn_s_barrier();    // all waves done reading buf[cur] too
    cur ^= 1;
  }
  COMPUTE(cur);                      // last tile, no prefetch

  // ---- epilogue: scale + bias, C/D layout: col=lane&15, row=(lane>>4)*4+reg
  float amax = __uint_as_float(*amax_bits);
  float scale = FP8MAX / fmaxf(amax, 1e-12f);
  float xs = 1.0f / scale;
  float cs = xs * wscale_p[0];
  const int orow = bm + wr * 64;
  const int ocol = bn + wc * 64;
  #pragma unroll
  for (int m = 0; m < 4; ++m) {
    #pragma unroll
    for (int n = 0; n < 4; ++n) {
      const int col = ocol + n * 16 + fr;
      const float bv = bias[col];
      #pragma unroll
      for (int i = 0; i < 4; ++i) {
        const int row = orow + m * 16 + q * 4 + i;
        out[(size_t)row * N_ + col] = acc[m][n][i] * cs + bv;
      }
    }
  }
}

extern "C" void kernel_launch(void* const* d_in, const int* in_sizes, int n_in,
                              void* d_out, int out_size, void* d_ws, size_t ws_size,
                              hipStream_t stream) {
  const float* x       = (const float*)d_in[0];
  const float* qweight = (const float*)d_in[1];
  const float* wscale  = (const float*)d_in[2];
  const float* bias    = (const float*)d_in[3];
  float* out = (float*)d_out;

  // ws layout: [0:4) amax bits | [256: 256+8KB) partial maxes | [16384: +16MB) qx | then qw
  u32*   amax_bits = (u32*)d_ws;
  float* partial   = (float*)((u8*)d_ws + 256);
  u8* qx = (u8*)d_ws + 16384;
  u8* qw = qx + (size_t)M_ * K_;

  amax_partial_kernel<<<AMAX_BLOCKS, 256, 0, stream>>>(x, partial, M_ * K_ / 4);
  amax_final_kernel<<<1, 256, 0, stream>>>(partial, amax_bits, AMAX_BLOCKS);
  quant_x_kernel<<<2048, 256, 0, stream>>>(x, amax_bits, (u32*)qx, M_ * K_ / 4);
  quant_w_kernel<<<2048, 256, 0, stream>>>(qweight, (u32*)qw, N_ * K_ / 4);
  dim3 grid(N_ / 128, M_ / 128);
  gemm_fp8_kernel<<<grid, 256, 0, stream>>>(qx, qw, amax_bits, wscale, bias, out);
}

// Round 12
// 186.057 us; speedup vs baseline: 1.4755x; 1.0264x over previous
//
#include <hip/hip_runtime.h>

// FP8DynamicLinear: x[8192,2048] fp32 -> dynamic per-tensor fp8 quant,
// qweight[2048,2048] (fp8-representable fp32), out = (qx*xs) @ (qw*ws)^T + bias.
static constexpr int M_ = 8192;
static constexpr int K_ = 2048;
static constexpr int N_ = 2048;
static constexpr int AMAX_BLOCKS = 2048;
static constexpr int QW_BLOCKS = 512;

#define FP8MAX 448.0f

using f32x4 = __attribute__((ext_vector_type(4))) float;
typedef unsigned int u32;
typedef unsigned char u8;

__device__ __forceinline__ void gload_lds16(const void* g, void* lds) {
  __builtin_amdgcn_global_load_lds((const __attribute__((address_space(1))) void*)g,
                                   (__attribute__((address_space(3))) void*)lds,
                                   16 /*bytes*/, 0 /*offset*/, 0 /*aux*/);
}

// ---------------- pass 1 (fused): per-block partial amax(|x|)  +  quant_w ----------------
// Blocks [0, AMAX_BLOCKS): partial amax of x (no global atomics).
// Blocks [AMAX_BLOCKS, AMAX_BLOCKS+QW_BLOCKS): cast qweight -> fp8 bytes (independent work).
__global__ void prep_kernel(const float* __restrict__ x, float* __restrict__ partial,
                            const float* __restrict__ wsrc, u32* __restrict__ qw,
                            int n4x, int n4w) {
  __shared__ float smax[4];
  if (blockIdx.x < AMAX_BLOCKS) {
    const float4* x4 = (const float4*)x;
    float m = 0.f;
    int idx = blockIdx.x * blockDim.x + threadIdx.x;
    int stride = AMAX_BLOCKS * blockDim.x;
    for (int i = idx; i < n4x; i += stride) {
      float4 v = x4[i];
      m = fmaxf(m, fmaxf(fmaxf(fabsf(v.x), fabsf(v.y)), fmaxf(fabsf(v.z), fabsf(v.w))));
    }
    #pragma unroll
    for (int off = 32; off > 0; off >>= 1) m = fmaxf(m, __shfl_xor(m, off, 64));
    const int wave = threadIdx.x >> 6;
    if ((threadIdx.x & 63) == 0) smax[wave] = m;
    __syncthreads();
    if (threadIdx.x == 0)
      partial[blockIdx.x] = fmaxf(fmaxf(smax[0], smax[1]), fmaxf(smax[2], smax[3]));
  } else {
    const f32x4* w4 = (const f32x4*)wsrc;
    int idx = (blockIdx.x - AMAX_BLOCKS) * blockDim.x + threadIdx.x;
    int stride = QW_BLOCKS * blockDim.x;
    for (int i = idx; i < n4w; i += stride) {
      f32x4 v = w4[i];
      int p = __builtin_amdgcn_cvt_pk_fp8_f32(v[0], v[1], 0, false);
      p = __builtin_amdgcn_cvt_pk_fp8_f32(v[2], v[3], p, true);
      qw[i] = (u32)p;
    }
  }
}

// ---------------- pass 2: quantize x -> fp8 e4m3 (RNE, matches clip+cast) ----------------
// Each block inline-reduces the 2048 partials (8 KB, L2-hot) -> amax; block 0 publishes
// amax_bits for the GEMM epilogue. Then unit-stride quant loop (float4/lane).
__global__ void quant_x_kernel(const float* __restrict__ x, const float* __restrict__ partial,
                               u32* __restrict__ amax_bits, u32* __restrict__ qx, int n4) {
  __shared__ float smax[4];
  float m = 0.f;
  for (int i = threadIdx.x; i < AMAX_BLOCKS; i += blockDim.x) m = fmaxf(m, partial[i]);
  #pragma unroll
  for (int off = 32; off > 0; off >>= 1) m = fmaxf(m, __shfl_xor(m, off, 64));
  const int wave = threadIdx.x >> 6;
  if ((threadIdx.x & 63) == 0) smax[wave] = m;
  __syncthreads();
  float amax = fmaxf(fmaxf(smax[0], smax[1]), fmaxf(smax[2], smax[3]));
  if (blockIdx.x == 0 && threadIdx.x == 0) amax_bits[0] = __float_as_uint(amax);

  float scale = FP8MAX / fmaxf(amax, 1e-12f);
  const f32x4* x4 = (const f32x4*)x;
  int idx = blockIdx.x * blockDim.x + threadIdx.x;
  int stride = gridDim.x * blockDim.x;
  for (int i = idx; i < n4; i += stride) {
    f32x4 v = x4[i];
    #pragma unroll
    for (int e = 0; e < 4; ++e) v[e] = fminf(fmaxf(v[e] * scale, -FP8MAX), FP8MAX);
    int p = __builtin_amdgcn_cvt_pk_fp8_f32(v[0], v[1], 0, false);
    p = __builtin_amdgcn_cvt_pk_fp8_f32(v[2], v[3], p, true);
    qx[i] = (u32)p;
  }
}

// ---------------- pass 3: fp8 GEMM, C = (qx qw^T) * (xs*ws) + bias ----------------
// 128x128 tile, BK=64 bytes, 4 waves (2x2), 16x16x32 fp8 MFMA.
// Minimum 2-phase pipeline (catalog T3-min, m248v2): double-buffered LDS;
// STAGE(t+1) issued BEFORE compute(t); raw s_barrier + explicit vmcnt(0) once per tile.
// LDS swizzle: chunk ^= (row>>2)&3 via pre-swizzled GLOBAL source (rule 21).
//   Verified at floor: SQ_LDS_BANK_CONFLICT = exactly 4/b64-read (structural passes).
// __launch_bounds__(256,4): 4 blocks/CU (VGPR 56, LDS 32 KiB -> feasible); R9 ran at
// 31% occupancy with (256,2) — more co-resident blocks cover the vmcnt drain (m114).
__global__ __launch_bounds__(256, 4) void gemm_fp8_kernel(
    const u8* __restrict__ qx, const u8* __restrict__ qw,
    const u32* __restrict__ amax_bits, const float* __restrict__ wscale_p,
    const float* __restrict__ bias, float* __restrict__ out)
{
  constexpr int BM = 128, BN = 128, BK = 64;
  constexpr int NT = K_ / BK;  // 32
  __shared__ u8 As[2][BM * BK];
  __shared__ u8 Bs[2][BN * BK];

  const int tid  = threadIdx.x;
  const int wave = tid >> 6;
  const int lane = tid & 63;
  const int bm = blockIdx.y * BM;
  const int bn = blockIdx.x * BN;

  // ---- staging addressing: thread tid stages 16B chunk `tid` (call 0) and `tid+256` (call 1)
  const int sr = tid >> 2;                      // LDS row 0..63 (call 0), +64 for call 1
  const int sc = tid & 3;                       // 16B chunk-in-row
  const int swzc = (sc ^ ((sr >> 2) & 3)) << 4; // pre-swizzled global byte offset in row
  const u8* gA0 = qx + (size_t)(bm + sr) * K_ + swzc;
  const u8* gA1 = gA0 + (size_t)64 * K_;
  const u8* gB0 = qw + (size_t)(bn + sr) * K_ + swzc;
  const u8* gB1 = gB0 + (size_t)64 * K_;
  const int ldsOff0 = wave * 1024;              // wave-uniform LDS bases
  const int ldsOff1 = 4096 + wave * 1024;

  // ---- fragment addressing
  const int wr = wave >> 1, wc = wave & 1;
  const int fr = lane & 15;                     // row within 16x16 tile
  const int q  = lane >> 4;                     // k-group
  const int swz = ((fr >> 2) & 3) << 4;         // read-side un-swizzle ((row>>2)&3 == (fr>>2)&3)
  int rowA[4], rowB[4];
  #pragma unroll
  for (int m = 0; m < 4; ++m) rowA[m] = (wr * 64 + m * 16 + fr) * BK;
  #pragma unroll
  for (int n = 0; n < 4; ++n) rowB[n] = (wc * 64 + n * 16 + fr) * BK;

  f32x4 acc[4][4];
  #pragma unroll
  for (int m = 0; m < 4; ++m)
    #pragma unroll
    for (int n = 0; n < 4; ++n)
      acc[m][n] = f32x4{0.f, 0.f, 0.f, 0.f};

  auto STAGE = [&](int buf) {
    gload_lds16(gA0, &As[buf][ldsOff0]);
    gload_lds16(gA1, &As[buf][ldsOff1]);
    gload_lds16(gB0, &Bs[buf][ldsOff0]);
    gload_lds16(gB1, &Bs[buf][ldsOff1]);
    gA0 += BK; gA1 += BK; gB0 += BK; gB1 += BK;
  };

  auto COMPUTE = [&](int buf) {
    #pragma unroll
    for (int ks = 0; ks < 2; ++ks) {
      const int kb = (ks * 32 + q * 8) ^ swz;
      long a[4], b[4];
      #pragma unroll
      for (int m = 0; m < 4; ++m) a[m] = *(const long*)(&As[buf][0] + rowA[m] + kb);
      #pragma unroll
      for (int n = 0; n < 4; ++n) b[n] = *(const long*)(&Bs[buf][0] + rowB[n] + kb);
      #pragma unroll
      for (int m = 0; m < 4; ++m)
        #pragma unroll
        for (int n = 0; n < 4; ++n)
          acc[m][n] = __builtin_amdgcn_mfma_f32_16x16x32_fp8_fp8(a[m], b[n], acc[m][n], 0, 0, 0);
    }
  };

  // prologue: stage tile 0, wait, barrier
  STAGE(0);
  asm volatile("s_waitcnt vmcnt(0)" ::: "memory");
  __builtin_amdgcn_s_barrier();

  int cur = 0;
  for (int kt = 0; kt < NT - 1; ++kt) {
    STAGE(cur ^ 1);                  // issue next-tile loads (stay in flight over MFMA)
    COMPUTE(cur);                    // ds_read + MFMA on current tile
    asm volatile("s_waitcnt vmcnt(0)" ::: "memory");  // prefetch landed
    __builtin_amdgcn_s_barrier();    // all waves done reading buf[cur] too
    cur ^= 1;
  }
  COMPUTE(cur);                      // last tile, no prefetch

  // ---- epilogue: scale + bias, C/D layout: col=lane&15, row=(lane>>4)*4+reg
  float amax = __uint_as_float(*amax_bits);
  float scale = FP8MAX / fmaxf(amax, 1e-12f);
  float xs = 1.0f / scale;
  float cs = xs * wscale_p[0];
  const int orow = bm + wr * 64;
  const int ocol = bn + wc * 64;
  #pragma unroll
  for (int m = 0; m < 4; ++m) {
    #pragma unroll
    for (int n = 0; n < 4; ++n) {
      const int col = ocol + n * 16 + fr;
      const float bv = bias[col];
      #pragma unroll
      for (int i = 0; i < 4; ++i) {
        const int row = orow + m * 16 + q * 4 + i;
        out[(size_t)row * N_ + col] = acc[m][n][i] * cs + bv;
      }
    }
  }
}

extern "C" void kernel_launch(void* const* d_in, const int* in_sizes, int n_in,
                              void* d_out, int out_size, void* d_ws, size_t ws_size,
                              hipStream_t stream) {
  const float* x       = (const float*)d_in[0];
  const float* qweight = (const float*)d_in[1];
  const float* wscale  = (const float*)d_in[2];
  const float* bias    = (const float*)d_in[3];
  float* out = (float*)d_out;

  // ws layout: [0:4) amax bits | [256: 256+8KB) partial maxes | [16384: +16MB) qx | then qw
  u32*   amax_bits = (u32*)d_ws;
  float* partial   = (float*)((u8*)d_ws + 256);
  u8* qx = (u8*)d_ws + 16384;
  u8* qw = qx + (size_t)M_ * K_;

  prep_kernel<<<AMAX_BLOCKS + QW_BLOCKS, 256, 0, stream>>>(x, partial, qweight, (u32*)qw,
                                                           M_ * K_ / 4, N_ * K_ / 4);
  quant_x_kernel<<<2048, 256, 0, stream>>>(x, partial, amax_bits, (u32*)qx, M_ * K_ / 4);
  dim3 grid(N_ / 128, M_ / 128);
  gemm_fp8_kernel<<<grid, 256, 0, stream>>>(qx, qw, amax_bits, wscale, bias, out);
}